// Round 1
// baseline (754.128 us; speedup 1.0000x reference)
//
#include <hip/hip_runtime.h>
#include <hip/hip_bf16.h>

// Problem constants (B=2, N=2048 -> T=4096 tokens)
#define TTOK  4096
#define CDIM  1024
#define FFDIM 4096
#define NEXP  8

// Workspace layout (assumes ws_size >= 81 MB):
//   [0,32)        counts[8]            (zeroed via memset each launch)
//   [64,100)      offsets[9]
//   [4K, 4K+128K) btok[8][4096]
//   [+128K,+256K) bgate[8][4096]
//   [1MB, 9MB)    xb: x as bf16 [4096,1024]
//   [16MB, 80MB)  H : gelu(X W1^T + b1) bf16, compacted [8192, 4096]

typedef short short8 __attribute__((ext_vector_type(8)));   // 8 bf16 in 4 VGPRs
typedef float f32x4 __attribute__((ext_vector_type(4)));

__device__ __forceinline__ unsigned short f2bf(float f) {
    unsigned int u = __float_as_uint(f);
    u = u + 0x7fffu + ((u >> 16) & 1u);   // round-to-nearest-even
    return (unsigned short)(u >> 16);
}

// ---------------- cast x -> bf16 ----------------
__global__ void cast_x_kernel(const float* __restrict__ x, unsigned short* __restrict__ xb) {
    int i = blockIdx.x * blockDim.x + threadIdx.x;   // 1,048,576 threads, 4 elems each
    float4 v = reinterpret_cast<const float4*>(x)[i];
    ushort4 o;
    o.x = f2bf(v.x); o.y = f2bf(v.y); o.z = f2bf(v.z); o.w = f2bf(v.w);
    reinterpret_cast<ushort4*>(xb)[i] = o;
}

// ---------------- router: logits -> softmax -> top2 -> bucket scatter ----------------
__global__ void router_kernel(const float* __restrict__ x, const float* __restrict__ rw,
                              int* __restrict__ counts, int* __restrict__ btok,
                              float* __restrict__ bgate) {
    const int wave = threadIdx.x >> 6;
    const int lane = threadIdx.x & 63;
    const int t = blockIdx.x * 4 + wave;
    const float* xr = x + (size_t)t * CDIM;

    float acc[NEXP];
#pragma unroll
    for (int e = 0; e < NEXP; e++) acc[e] = 0.f;
    for (int c = lane; c < CDIM; c += 64) {
        float xv = xr[c];
#pragma unroll
        for (int e = 0; e < NEXP; e++) acc[e] += xv * rw[e * CDIM + c];
    }
#pragma unroll
    for (int e = 0; e < NEXP; e++) {
#pragma unroll
        for (int off = 32; off > 0; off >>= 1) acc[e] += __shfl_down(acc[e], off, 64);
    }
    if (lane == 0) {
        float mx = acc[0];
#pragma unroll
        for (int e = 1; e < NEXP; e++) mx = fmaxf(mx, acc[e]);
        float p[NEXP]; float s = 0.f;
#pragma unroll
        for (int e = 0; e < NEXP; e++) { p[e] = expf(acc[e] - mx); s += p[e]; }
        int i0 = 0;
#pragma unroll
        for (int e = 1; e < NEXP; e++) if (p[e] > p[i0]) i0 = e;
        int i1 = (i0 == 0) ? 1 : 0;
#pragma unroll
        for (int e = 0; e < NEXP; e++) if (e != i0 && p[e] > p[i1]) i1 = e;
        float pr0 = p[i0] / s, pr1 = p[i1] / s;
        float rs = 1.f / (pr0 + pr1 + 1e-9f);
        float w0 = pr0 * rs, w1 = pr1 * rs;
        int pos = atomicAdd(&counts[i0], 1);
        btok[i0 * TTOK + pos] = t; bgate[i0 * TTOK + pos] = w0;
        pos = atomicAdd(&counts[i1], 1);
        btok[i1 * TTOK + pos] = t; bgate[i1 * TTOK + pos] = w1;
    }
}

__global__ void offsets_kernel(const int* __restrict__ counts, int* __restrict__ offsets) {
    if (threadIdx.x == 0 && blockIdx.x == 0) {
        int s = 0;
        for (int e = 0; e < NEXP; e++) { offsets[e] = s; s += counts[e]; }
        offsets[NEXP] = s;
    }
}

// ---------------- pass A: H = gelu(X W1^T + b1), bf16 MFMA 128x128 tiles ----------------
__global__ __launch_bounds__(256) void gemm1_kernel(
    const unsigned short* __restrict__ xb, const float* __restrict__ w1,
    const float* __restrict__ b1, const int* __restrict__ counts,
    const int* __restrict__ offsets, const int* __restrict__ btok,
    unsigned short* __restrict__ H) {
    const int e = blockIdx.z;
    const int cnt = counts[e];
    const int m0 = blockIdx.y * 128;
    if (m0 >= cnt) return;
    const int n0 = blockIdx.x * 128;   // FF columns
    const int po = offsets[e];

    __shared__ unsigned short As[128][32];
    __shared__ unsigned short Bs[128][32];

    const int tid = threadIdx.x;
    const int wave = tid >> 6, lane = tid & 63;
    const int wm = (wave >> 1) << 6, wn = (wave & 1) << 6;
    const int lm = lane & 15, kq = lane >> 4;

    f32x4 acc[4][4];
#pragma unroll
    for (int i = 0; i < 4; i++)
#pragma unroll
        for (int j = 0; j < 4; j++) { f32x4 z = {0.f, 0.f, 0.f, 0.f}; acc[i][j] = z; }

    const float* w1e = w1 + (size_t)e * FFDIM * CDIM;
    const int arow = tid >> 1;                // 0..127
    const int acolb = (tid & 1) * 16;         // 0 or 16 (elements)
    int tokA = -1;
    if (m0 + arow < cnt) tokA = btok[e * TTOK + m0 + arow];
    const int brow = tid >> 1;
    const int bcol = (tid & 1) * 16;

    for (int k0 = 0; k0 < CDIM; k0 += 32) {
        // A: 16 bf16 per thread (one gathered token row slice)
        uint4 a0 = {0, 0, 0, 0}, a1 = {0, 0, 0, 0};
        if (tokA >= 0) {
            const uint4* src = reinterpret_cast<const uint4*>(xb + (size_t)tokA * CDIM + k0 + acolb);
            a0 = src[0]; a1 = src[1];
        }
        *reinterpret_cast<uint4*>(&As[arow][acolb]) = a0;
        *reinterpret_cast<uint4*>(&As[arow][acolb + 8]) = a1;
        // B: 16 fp32 per thread from W1 (row-major [FF, C] = N-major K-contig), cvt -> bf16
        {
            const float* src = w1e + (size_t)(n0 + brow) * CDIM + k0 + bcol;
            ushort4* dst = reinterpret_cast<ushort4*>(&Bs[brow][bcol]);
#pragma unroll
            for (int q = 0; q < 4; q++) {
                float4 v = reinterpret_cast<const float4*>(src)[q];
                ushort4 o; o.x = f2bf(v.x); o.y = f2bf(v.y); o.z = f2bf(v.z); o.w = f2bf(v.w);
                dst[q] = o;
            }
        }
        __syncthreads();
        short8 af[4], bfr[4];
#pragma unroll
        for (int i = 0; i < 4; i++) af[i] = *reinterpret_cast<const short8*>(&As[wm + i * 16 + lm][kq * 8]);
#pragma unroll
        for (int j = 0; j < 4; j++) bfr[j] = *reinterpret_cast<const short8*>(&Bs[wn + j * 16 + lm][kq * 8]);
#pragma unroll
        for (int i = 0; i < 4; i++)
#pragma unroll
            for (int j = 0; j < 4; j++)
                acc[i][j] = __builtin_amdgcn_mfma_f32_16x16x32_bf16(af[i], bfr[j], acc[i][j], 0, 0, 0);
        __syncthreads();
    }

    // epilogue: D row = m (quad*4+reg), col = n (lane&15); add b1, exact gelu, store bf16
#pragma unroll
    for (int j = 0; j < 4; j++) {
        const int fcol = n0 + wn + j * 16 + lm;
        const float bias = b1[e * FFDIM + fcol];
#pragma unroll
        for (int i = 0; i < 4; i++) {
#pragma unroll
            for (int r = 0; r < 4; r++) {
                const int mrow = m0 + wm + i * 16 + kq * 4 + r;
                if (mrow < cnt) {
                    float h = acc[i][j][r] + bias;
                    float g = 0.5f * h * (1.f + erff(h * 0.70710678118654752f));
                    H[(size_t)(po + mrow) * FFDIM + fcol] = f2bf(g);
                }
            }
        }
    }
}

// ---------------- pass B: out += gate * (H W2^T + b2), atomic scatter ----------------
__global__ __launch_bounds__(256) void gemm2_kernel(
    const unsigned short* __restrict__ H, const float* __restrict__ w2,
    const float* __restrict__ b2, const int* __restrict__ counts,
    const int* __restrict__ offsets, const int* __restrict__ btok,
    const float* __restrict__ bgate, float* __restrict__ out) {
    const int e = blockIdx.z;
    const int cnt = counts[e];
    const int m0 = blockIdx.y * 128;
    if (m0 >= cnt) return;
    const int n0 = blockIdx.x * 128;   // C columns
    const int po = offsets[e];

    __shared__ unsigned short As[128][32];
    __shared__ unsigned short Bs[128][32];

    const int tid = threadIdx.x;
    const int wave = tid >> 6, lane = tid & 63;
    const int wm = (wave >> 1) << 6, wn = (wave & 1) << 6;
    const int lm = lane & 15, kq = lane >> 4;

    f32x4 acc[4][4];
#pragma unroll
    for (int i = 0; i < 4; i++)
#pragma unroll
        for (int j = 0; j < 4; j++) { f32x4 z = {0.f, 0.f, 0.f, 0.f}; acc[i][j] = z; }

    const float* w2e = w2 + (size_t)e * CDIM * FFDIM;
    const int arow = tid >> 1;
    const int acolb = (tid & 1) * 16;
    const bool aval = (m0 + arow < cnt);
    const unsigned short* asrc = H + (size_t)(po + m0 + arow) * FFDIM + acolb;
    const int brow = tid >> 1;
    const int bcol = (tid & 1) * 16;

    for (int k0 = 0; k0 < FFDIM; k0 += 32) {
        uint4 a0 = {0, 0, 0, 0}, a1 = {0, 0, 0, 0};
        if (aval) {
            const uint4* src = reinterpret_cast<const uint4*>(asrc + k0);
            a0 = src[0]; a1 = src[1];
        }
        *reinterpret_cast<uint4*>(&As[arow][acolb]) = a0;
        *reinterpret_cast<uint4*>(&As[arow][acolb + 8]) = a1;
        {
            const float* src = w2e + (size_t)(n0 + brow) * FFDIM + k0 + bcol;
            ushort4* dst = reinterpret_cast<ushort4*>(&Bs[brow][bcol]);
#pragma unroll
            for (int q = 0; q < 4; q++) {
                float4 v = reinterpret_cast<const float4*>(src)[q];
                ushort4 o; o.x = f2bf(v.x); o.y = f2bf(v.y); o.z = f2bf(v.z); o.w = f2bf(v.w);
                dst[q] = o;
            }
        }
        __syncthreads();
        short8 af[4], bfr[4];
#pragma unroll
        for (int i = 0; i < 4; i++) af[i] = *reinterpret_cast<const short8*>(&As[wm + i * 16 + lm][kq * 8]);
#pragma unroll
        for (int j = 0; j < 4; j++) bfr[j] = *reinterpret_cast<const short8*>(&Bs[wn + j * 16 + lm][kq * 8]);
#pragma unroll
        for (int i = 0; i < 4; i++)
#pragma unroll
            for (int j = 0; j < 4; j++)
                acc[i][j] = __builtin_amdgcn_mfma_f32_16x16x32_bf16(af[i], bfr[j], acc[i][j], 0, 0, 0);
        __syncthreads();
    }

    float bias[4];
#pragma unroll
    for (int j = 0; j < 4; j++) bias[j] = b2[e * CDIM + n0 + wn + j * 16 + lm];

#pragma unroll
    for (int i = 0; i < 4; i++) {
#pragma unroll
        for (int r = 0; r < 4; r++) {
            const int mrow = m0 + wm + i * 16 + kq * 4 + r;
            if (mrow < cnt) {
                const int tok = btok[e * TTOK + mrow];
                const float g = bgate[e * TTOK + mrow];
                float* orow = out + (size_t)tok * CDIM;
#pragma unroll
                for (int j = 0; j < 4; j++) {
                    const int c = n0 + wn + j * 16 + lm;
                    atomicAdd(orow + c, g * (acc[i][j][r] + bias[j]));
                }
            }
        }
    }
}

extern "C" void kernel_launch(void* const* d_in, const int* in_sizes, int n_in,
                              void* d_out, int out_size, void* d_ws, size_t ws_size,
                              hipStream_t stream) {
    const float* x  = (const float*)d_in[0];
    const float* rw = (const float*)d_in[1];
    const float* w1 = (const float*)d_in[2];
    const float* b1 = (const float*)d_in[3];
    const float* w2 = (const float*)d_in[4];
    const float* b2 = (const float*)d_in[5];
    float* out = (float*)d_out;

    char* ws = (char*)d_ws;
    int*   counts  = (int*)ws;
    int*   offsets = (int*)(ws + 64);
    int*   btok    = (int*)(ws + 4096);
    float* bgate   = (float*)(ws + 4096 + 131072);
    unsigned short* xb = (unsigned short*)(ws + (1u << 20));
    unsigned short* H  = (unsigned short*)(ws + (16u << 20));

    hipMemsetAsync(d_out, 0, (size_t)out_size * sizeof(float), stream);
    hipMemsetAsync(counts, 0, 64, stream);

    cast_x_kernel<<<(TTOK * CDIM) / (256 * 4), 256, 0, stream>>>(x, xb);
    router_kernel<<<TTOK / 4, 256, 0, stream>>>(x, rw, counts, btok, bgate);
    offsets_kernel<<<1, 64, 0, stream>>>(counts, offsets);
    gemm1_kernel<<<dim3(FFDIM / 128, TTOK / 128, NEXP), 256, 0, stream>>>(
        xb, w1, b1, counts, offsets, btok, H);
    gemm2_kernel<<<dim3(CDIM / 128, TTOK / 128, NEXP), 256, 0, stream>>>(
        H, w2, b2, counts, offsets, btok, bgate, out);
}

// Round 2
// 708.374 us; speedup vs baseline: 1.0646x; 1.0646x over previous
//
#include <hip/hip_runtime.h>
#include <hip/hip_bf16.h>
#include <cstdint>

// Problem constants (B=2, N=2048 -> T=4096 tokens)
#define TTOK  4096
#define CDIM  1024
#define FFDIM 4096
#define NEXP  8

// Fast-path workspace layout (needs >= 137 MiB):
//   [0,64)            counts[8]   (memset 0 each launch)
//   [64, ..)          offsets[9]
//   [4K, 4K+128K)     btok[8][4096]
//   [132K, 132K+128K) bgate[8][4096]
//   [1MB, 9MB)        xb : x as bf16 [4096,1024]
//   [9MB, 73MB)       Wb : bf16 weights, shared between passes (W1 then W2), 64 MiB
//   [73MB, 137MB)     H  : gelu(X W1^T + b1) bf16, compacted [8192, 4096], 64 MiB
// Slow fallback (round-1 kernels) needs ~80 MiB: xb@1MB, H@16MB.

typedef short short8 __attribute__((ext_vector_type(8)));   // 8 bf16 in 4 VGPRs
typedef float f32x4 __attribute__((ext_vector_type(4)));

__device__ __forceinline__ unsigned short f2bf(float f) {
    unsigned int u = __float_as_uint(f);
    u = u + 0x7fffu + ((u >> 16) & 1u);   // round-to-nearest-even
    return (unsigned short)(u >> 16);
}

// async global -> LDS, 16 bytes per lane. LDS dest MUST be wave-uniform base + lane*16.
__device__ __forceinline__ void gl_lds16(const unsigned short* g, unsigned short* l) {
    __builtin_amdgcn_global_load_lds(
        (const __attribute__((address_space(1))) unsigned int*)g,
        (__attribute__((address_space(3))) unsigned int*)l, 16, 0, 0);
}

// ---------------- fp32 -> bf16 cast (x and weights) ----------------
__global__ void cast_kernel(const float* __restrict__ src, unsigned short* __restrict__ dst) {
    int i = blockIdx.x * blockDim.x + threadIdx.x;   // n/4 threads, exact division
    float4 v = reinterpret_cast<const float4*>(src)[i];
    ushort4 o;
    o.x = f2bf(v.x); o.y = f2bf(v.y); o.z = f2bf(v.z); o.w = f2bf(v.w);
    reinterpret_cast<ushort4*>(dst)[i] = o;
}

// ---------------- router: logits -> softmax -> top2 -> bucket scatter ----------------
__global__ void router_kernel(const float* __restrict__ x, const float* __restrict__ rw,
                              int* __restrict__ counts, int* __restrict__ btok,
                              float* __restrict__ bgate) {
    const int wave = threadIdx.x >> 6;
    const int lane = threadIdx.x & 63;
    const int t = blockIdx.x * 4 + wave;
    const float* xr = x + (size_t)t * CDIM;

    float acc[NEXP];
#pragma unroll
    for (int e = 0; e < NEXP; e++) acc[e] = 0.f;
    for (int c = lane; c < CDIM; c += 64) {
        float xv = xr[c];
#pragma unroll
        for (int e = 0; e < NEXP; e++) acc[e] += xv * rw[e * CDIM + c];
    }
#pragma unroll
    for (int e = 0; e < NEXP; e++) {
#pragma unroll
        for (int off = 32; off > 0; off >>= 1) acc[e] += __shfl_down(acc[e], off, 64);
    }
    if (lane == 0) {
        float mx = acc[0];
#pragma unroll
        for (int e = 1; e < NEXP; e++) mx = fmaxf(mx, acc[e]);
        float p[NEXP]; float s = 0.f;
#pragma unroll
        for (int e = 0; e < NEXP; e++) { p[e] = expf(acc[e] - mx); s += p[e]; }
        int i0 = 0;
#pragma unroll
        for (int e = 1; e < NEXP; e++) if (p[e] > p[i0]) i0 = e;
        int i1 = (i0 == 0) ? 1 : 0;
#pragma unroll
        for (int e = 0; e < NEXP; e++) if (e != i0 && p[e] > p[i1]) i1 = e;
        float pr0 = p[i0] / s, pr1 = p[i1] / s;
        float rs = 1.f / (pr0 + pr1 + 1e-9f);
        float w0 = pr0 * rs, w1 = pr1 * rs;
        int pos = atomicAdd(&counts[i0], 1);
        btok[i0 * TTOK + pos] = t; bgate[i0 * TTOK + pos] = w0;
        pos = atomicAdd(&counts[i1], 1);
        btok[i1 * TTOK + pos] = t; bgate[i1 * TTOK + pos] = w1;
    }
}

__global__ void offsets_kernel(const int* __restrict__ counts, int* __restrict__ offsets) {
    if (threadIdx.x == 0 && blockIdx.x == 0) {
        int s = 0;
        for (int e = 0; e < NEXP; e++) { offsets[e] = s; s += counts[e]; }
        offsets[NEXP] = s;
    }
}

// ================= FAST PATH (m97 structure: global_load_lds width=16) =================

// pass A: H = gelu(X W1b^T + b1), 128x128 tile, BK=32, coalesced LDS-repacked store
__global__ __launch_bounds__(256) void gemm1f_kernel(
    const unsigned short* __restrict__ xb, const unsigned short* __restrict__ w1b,
    const float* __restrict__ b1, const int* __restrict__ counts,
    const int* __restrict__ offsets, const int* __restrict__ btok,
    unsigned short* __restrict__ H) {
    const int e = blockIdx.z;
    const int cnt = counts[e];
    const int m0 = blockIdx.y * 128;
    if (m0 >= cnt) return;
    const int n0 = blockIdx.x * 128;   // FF columns
    const int po = offsets[e];

    __shared__ unsigned short As[128 * 32];   // 8 KB, unpadded (global_load_lds layout)
    __shared__ unsigned short Bs[128 * 32];   // 8 KB
    __shared__ unsigned short Cs[64 * 128];   // 16 KB output repack buffer

    const int tid = threadIdx.x;
    const int wave = tid >> 6, lane = tid & 63;
    const int wm = (wave >> 1) << 6, wn = (wave & 1) << 6;
    const int lm = lane & 15, kq = lane >> 4;

    // staging: thread covers 16 B = 8 bf16; row = tid/4 (+64), col8 = (tid%4)*8
    const int sr = tid >> 2;
    const int sc = (tid & 3) << 3;
    const int tA0 = btok[e * TTOK + min(m0 + sr, cnt - 1)];
    const int tA1 = btok[e * TTOK + min(m0 + 64 + sr, cnt - 1)];
    const unsigned short* ga0 = xb + (size_t)tA0 * CDIM + sc;
    const unsigned short* ga1 = xb + (size_t)tA1 * CDIM + sc;
    const unsigned short* gb0 = w1b + ((size_t)e * FFDIM + n0 + sr) * CDIM + sc;
    const unsigned short* gb1 = gb0 + (size_t)64 * CDIM;
    unsigned short* lA = &As[tid * 8];        // tid*16 bytes
    unsigned short* lB = &Bs[tid * 8];

    f32x4 acc[4][4];
#pragma unroll
    for (int i = 0; i < 4; i++)
#pragma unroll
        for (int j = 0; j < 4; j++) { f32x4 z = {0.f, 0.f, 0.f, 0.f}; acc[i][j] = z; }

    for (int k0 = 0; k0 < CDIM; k0 += 32) {
        gl_lds16(ga0 + k0, lA);
        gl_lds16(ga1 + k0, lA + 64 * 32);
        gl_lds16(gb0 + k0, lB);
        gl_lds16(gb1 + k0, lB + 64 * 32);
        __syncthreads();
        short8 af[4], bfr[4];
#pragma unroll
        for (int i = 0; i < 4; i++) af[i] = *reinterpret_cast<const short8*>(&As[(wm + i * 16 + lm) * 32 + kq * 8]);
#pragma unroll
        for (int j = 0; j < 4; j++) bfr[j] = *reinterpret_cast<const short8*>(&Bs[(wn + j * 16 + lm) * 32 + kq * 8]);
#pragma unroll
        for (int i = 0; i < 4; i++)
#pragma unroll
            for (int j = 0; j < 4; j++)
                acc[i][j] = __builtin_amdgcn_mfma_f32_16x16x32_bf16(af[i], bfr[j], acc[i][j], 0, 0, 0);
        __syncthreads();
    }

    float bias[4];
#pragma unroll
    for (int j = 0; j < 4; j++) bias[j] = b1[e * FFDIM + n0 + wn + j * 16 + lm];

    // epilogue: gelu + repack 64 rows at a time through LDS, then coalesced uint4 stores
#pragma unroll
    for (int p = 0; p < 2; p++) {
        if ((wave >> 1) == p) {
#pragma unroll
            for (int i = 0; i < 4; i++) {
#pragma unroll
                for (int r = 0; r < 4; r++) {
                    const int row = i * 16 + kq * 4 + r;   // 0..63 relative to p*64
#pragma unroll
                    for (int j = 0; j < 4; j++) {
                        float h = acc[i][j][r] + bias[j];
                        float g = 0.5f * h * (1.f + erff(h * 0.70710678118654752f));
                        Cs[row * 128 + wn + j * 16 + lm] = f2bf(g);
                    }
                }
            }
        }
        __syncthreads();
#pragma unroll
        for (int q = 0; q < 4; q++) {
            const int c = q * 256 + tid;
            const int row = c >> 4;
            const int col8 = (c & 15) << 3;
            const int mrow = m0 + p * 64 + row;
            if (mrow < cnt)
                *reinterpret_cast<uint4*>(&H[(size_t)(po + mrow) * FFDIM + n0 + col8]) =
                    *reinterpret_cast<const uint4*>(&Cs[row * 128 + col8]);
        }
        __syncthreads();
    }
}

// pass B: out += gate * (H W2b^T + b2), split-K=2, atomic scatter epilogue
__global__ __launch_bounds__(256) void gemm2f_kernel(
    const unsigned short* __restrict__ H, const unsigned short* __restrict__ w2b,
    const float* __restrict__ b2, const int* __restrict__ counts,
    const int* __restrict__ offsets, const int* __restrict__ btok,
    const float* __restrict__ bgate, float* __restrict__ out) {
    const int e = blockIdx.z;
    const int cnt = counts[e];
    const int m0 = (blockIdx.y >> 1) * 128;
    const int ks = blockIdx.y & 1;             // K split: [ks*2048, ks*2048+2048)
    if (m0 >= cnt) return;
    const int n0 = blockIdx.x * 128;           // C columns
    const int po = offsets[e];

    __shared__ unsigned short As[128 * 32];
    __shared__ unsigned short Bs[128 * 32];

    const int tid = threadIdx.x;
    const int wave = tid >> 6, lane = tid & 63;
    const int wm = (wave >> 1) << 6, wn = (wave & 1) << 6;
    const int lm = lane & 15, kq = lane >> 4;

    const int sr = tid >> 2;
    const int sc = (tid & 3) << 3;
    const int r0 = min(m0 + sr, cnt - 1);
    const int r1 = min(m0 + 64 + sr, cnt - 1);
    const unsigned short* ga0 = H + (size_t)(po + r0) * FFDIM + ks * 2048 + sc;
    const unsigned short* ga1 = H + (size_t)(po + r1) * FFDIM + ks * 2048 + sc;
    const unsigned short* gb0 = w2b + ((size_t)e * CDIM + n0 + sr) * FFDIM + ks * 2048 + sc;
    const unsigned short* gb1 = gb0 + (size_t)64 * FFDIM;
    unsigned short* lA = &As[tid * 8];
    unsigned short* lB = &Bs[tid * 8];

    f32x4 acc[4][4];
#pragma unroll
    for (int i = 0; i < 4; i++)
#pragma unroll
        for (int j = 0; j < 4; j++) { f32x4 z = {0.f, 0.f, 0.f, 0.f}; acc[i][j] = z; }

    for (int k0 = 0; k0 < 2048; k0 += 32) {
        gl_lds16(ga0 + k0, lA);
        gl_lds16(ga1 + k0, lA + 64 * 32);
        gl_lds16(gb0 + k0, lB);
        gl_lds16(gb1 + k0, lB + 64 * 32);
        __syncthreads();
        short8 af[4], bfr[4];
#pragma unroll
        for (int i = 0; i < 4; i++) af[i] = *reinterpret_cast<const short8*>(&As[(wm + i * 16 + lm) * 32 + kq * 8]);
#pragma unroll
        for (int j = 0; j < 4; j++) bfr[j] = *reinterpret_cast<const short8*>(&Bs[(wn + j * 16 + lm) * 32 + kq * 8]);
#pragma unroll
        for (int i = 0; i < 4; i++)
#pragma unroll
            for (int j = 0; j < 4; j++)
                acc[i][j] = __builtin_amdgcn_mfma_f32_16x16x32_bf16(af[i], bfr[j], acc[i][j], 0, 0, 0);
        __syncthreads();
    }

    float bias[4];
#pragma unroll
    for (int j = 0; j < 4; j++) bias[j] = (ks == 0) ? b2[e * CDIM + n0 + wn + j * 16 + lm] : 0.f;

#pragma unroll
    for (int i = 0; i < 4; i++) {
#pragma unroll
        for (int r = 0; r < 4; r++) {
            const int mrow = m0 + wm + i * 16 + kq * 4 + r;
            if (mrow < cnt) {
                const int tok = btok[e * TTOK + mrow];
                const float g = bgate[e * TTOK + mrow];
                float* orow = out + (size_t)tok * CDIM;
#pragma unroll
                for (int j = 0; j < 4; j++)
                    atomicAdd(orow + n0 + wn + j * 16 + lm, g * (acc[i][j][r] + bias[j]));
            }
        }
    }
}

// ================= SLOW FALLBACK (round-1 kernels, in-loop fp32->bf16) =================

__global__ __launch_bounds__(256) void gemm1_kernel(
    const unsigned short* __restrict__ xb, const float* __restrict__ w1,
    const float* __restrict__ b1, const int* __restrict__ counts,
    const int* __restrict__ offsets, const int* __restrict__ btok,
    unsigned short* __restrict__ H) {
    const int e = blockIdx.z;
    const int cnt = counts[e];
    const int m0 = blockIdx.y * 128;
    if (m0 >= cnt) return;
    const int n0 = blockIdx.x * 128;
    const int po = offsets[e];

    __shared__ unsigned short As[128][32];
    __shared__ unsigned short Bs[128][32];

    const int tid = threadIdx.x;
    const int wave = tid >> 6, lane = tid & 63;
    const int wm = (wave >> 1) << 6, wn = (wave & 1) << 6;
    const int lm = lane & 15, kq = lane >> 4;

    f32x4 acc[4][4];
#pragma unroll
    for (int i = 0; i < 4; i++)
#pragma unroll
        for (int j = 0; j < 4; j++) { f32x4 z = {0.f, 0.f, 0.f, 0.f}; acc[i][j] = z; }

    const float* w1e = w1 + (size_t)e * FFDIM * CDIM;
    const int arow = tid >> 1;
    const int acolb = (tid & 1) * 16;
    int tokA = -1;
    if (m0 + arow < cnt) tokA = btok[e * TTOK + m0 + arow];
    const int brow = tid >> 1;
    const int bcol = (tid & 1) * 16;

    for (int k0 = 0; k0 < CDIM; k0 += 32) {
        uint4 a0 = {0, 0, 0, 0}, a1 = {0, 0, 0, 0};
        if (tokA >= 0) {
            const uint4* src = reinterpret_cast<const uint4*>(xb + (size_t)tokA * CDIM + k0 + acolb);
            a0 = src[0]; a1 = src[1];
        }
        *reinterpret_cast<uint4*>(&As[arow][acolb]) = a0;
        *reinterpret_cast<uint4*>(&As[arow][acolb + 8]) = a1;
        {
            const float* src = w1e + (size_t)(n0 + brow) * CDIM + k0 + bcol;
            ushort4* dst = reinterpret_cast<ushort4*>(&Bs[brow][bcol]);
#pragma unroll
            for (int q = 0; q < 4; q++) {
                float4 v = reinterpret_cast<const float4*>(src)[q];
                ushort4 o; o.x = f2bf(v.x); o.y = f2bf(v.y); o.z = f2bf(v.z); o.w = f2bf(v.w);
                dst[q] = o;
            }
        }
        __syncthreads();
        short8 af[4], bfr[4];
#pragma unroll
        for (int i = 0; i < 4; i++) af[i] = *reinterpret_cast<const short8*>(&As[wm + i * 16 + lm][kq * 8]);
#pragma unroll
        for (int j = 0; j < 4; j++) bfr[j] = *reinterpret_cast<const short8*>(&Bs[wn + j * 16 + lm][kq * 8]);
#pragma unroll
        for (int i = 0; i < 4; i++)
#pragma unroll
            for (int j = 0; j < 4; j++)
                acc[i][j] = __builtin_amdgcn_mfma_f32_16x16x32_bf16(af[i], bfr[j], acc[i][j], 0, 0, 0);
        __syncthreads();
    }

#pragma unroll
    for (int j = 0; j < 4; j++) {
        const int fcol = n0 + wn + j * 16 + lm;
        const float bias = b1[e * FFDIM + fcol];
#pragma unroll
        for (int i = 0; i < 4; i++) {
#pragma unroll
            for (int r = 0; r < 4; r++) {
                const int mrow = m0 + wm + i * 16 + kq * 4 + r;
                if (mrow < cnt) {
                    float h = acc[i][j][r] + bias;
                    float g = 0.5f * h * (1.f + erff(h * 0.70710678118654752f));
                    H[(size_t)(po + mrow) * FFDIM + fcol] = f2bf(g);
                }
            }
        }
    }
}

__global__ __launch_bounds__(256) void gemm2_kernel(
    const unsigned short* __restrict__ H, const float* __restrict__ w2,
    const float* __restrict__ b2, const int* __restrict__ counts,
    const int* __restrict__ offsets, const int* __restrict__ btok,
    const float* __restrict__ bgate, float* __restrict__ out) {
    const int e = blockIdx.z;
    const int cnt = counts[e];
    const int m0 = blockIdx.y * 128;
    if (m0 >= cnt) return;
    const int n0 = blockIdx.x * 128;
    const int po = offsets[e];

    __shared__ unsigned short As[128][32];
    __shared__ unsigned short Bs[128][32];

    const int tid = threadIdx.x;
    const int wave = tid >> 6, lane = tid & 63;
    const int wm = (wave >> 1) << 6, wn = (wave & 1) << 6;
    const int lm = lane & 15, kq = lane >> 4;

    f32x4 acc[4][4];
#pragma unroll
    for (int i = 0; i < 4; i++)
#pragma unroll
        for (int j = 0; j < 4; j++) { f32x4 z = {0.f, 0.f, 0.f, 0.f}; acc[i][j] = z; }

    const float* w2e = w2 + (size_t)e * CDIM * FFDIM;
    const int arow = tid >> 1;
    const int acolb = (tid & 1) * 16;
    const bool aval = (m0 + arow < cnt);
    const unsigned short* asrc = H + (size_t)(po + m0 + arow) * FFDIM + acolb;
    const int brow = tid >> 1;
    const int bcol = (tid & 1) * 16;

    for (int k0 = 0; k0 < FFDIM; k0 += 32) {
        uint4 a0 = {0, 0, 0, 0}, a1 = {0, 0, 0, 0};
        if (aval) {
            const uint4* src = reinterpret_cast<const uint4*>(asrc + k0);
            a0 = src[0]; a1 = src[1];
        }
        *reinterpret_cast<uint4*>(&As[arow][acolb]) = a0;
        *reinterpret_cast<uint4*>(&As[arow][acolb + 8]) = a1;
        {
            const float* src = w2e + (size_t)(n0 + brow) * FFDIM + k0 + bcol;
            ushort4* dst = reinterpret_cast<ushort4*>(&Bs[brow][bcol]);
#pragma unroll
            for (int q = 0; q < 4; q++) {
                float4 v = reinterpret_cast<const float4*>(src)[q];
                ushort4 o; o.x = f2bf(v.x); o.y = f2bf(v.y); o.z = f2bf(v.z); o.w = f2bf(v.w);
                dst[q] = o;
            }
        }
        __syncthreads();
        short8 af[4], bfr[4];
#pragma unroll
        for (int i = 0; i < 4; i++) af[i] = *reinterpret_cast<const short8*>(&As[wm + i * 16 + lm][kq * 8]);
#pragma unroll
        for (int j = 0; j < 4; j++) bfr[j] = *reinterpret_cast<const short8*>(&Bs[wn + j * 16 + lm][kq * 8]);
#pragma unroll
        for (int i = 0; i < 4; i++)
#pragma unroll
            for (int j = 0; j < 4; j++)
                acc[i][j] = __builtin_amdgcn_mfma_f32_16x16x32_bf16(af[i], bfr[j], acc[i][j], 0, 0, 0);
        __syncthreads();
    }

    float bias[4];
#pragma unroll
    for (int j = 0; j < 4; j++) bias[j] = b2[e * CDIM + n0 + wn + j * 16 + lm];

#pragma unroll
    for (int i = 0; i < 4; i++) {
#pragma unroll
        for (int r = 0; r < 4; r++) {
            const int mrow = m0 + wm + i * 16 + kq * 4 + r;
            if (mrow < cnt) {
                const int tok = btok[e * TTOK + mrow];
                const float g = bgate[e * TTOK + mrow];
                float* orow = out + (size_t)tok * CDIM;
#pragma unroll
                for (int j = 0; j < 4; j++) {
                    const int c = n0 + wn + j * 16 + lm;
                    atomicAdd(orow + c, g * (acc[i][j][r] + bias[j]));
                }
            }
        }
    }
}

extern "C" void kernel_launch(void* const* d_in, const int* in_sizes, int n_in,
                              void* d_out, int out_size, void* d_ws, size_t ws_size,
                              hipStream_t stream) {
    const float* x  = (const float*)d_in[0];
    const float* rw = (const float*)d_in[1];
    const float* w1 = (const float*)d_in[2];
    const float* b1 = (const float*)d_in[3];
    const float* w2 = (const float*)d_in[4];
    const float* b2 = (const float*)d_in[5];
    float* out = (float*)d_out;

    char* ws = (char*)d_ws;
    int*   counts  = (int*)ws;
    int*   offsets = (int*)(ws + 64);
    int*   btok    = (int*)(ws + 4096);
    float* bgate   = (float*)(ws + 4096 + 131072);

    hipMemsetAsync(d_out, 0, (size_t)out_size * sizeof(float), stream);
    hipMemsetAsync(counts, 0, 64, stream);

    const bool fast = ws_size >= ((size_t)137 << 20);

    if (fast) {
        unsigned short* xb = (unsigned short*)(ws + ((size_t)1 << 20));
        unsigned short* Wb = (unsigned short*)(ws + ((size_t)9 << 20));    // 64 MiB shared W1b/W2b
        unsigned short* H  = (unsigned short*)(ws + ((size_t)73 << 20));   // 64 MiB

        cast_kernel<<<(TTOK * CDIM) / (256 * 4), 256, 0, stream>>>(x, xb);
        router_kernel<<<TTOK / 4, 256, 0, stream>>>(x, rw, counts, btok, bgate);
        offsets_kernel<<<1, 64, 0, stream>>>(counts, offsets);
        // W1 -> bf16, then gemm1; reuse Wb for W2 afterwards (stream-ordered)
        cast_kernel<<<(NEXP * FFDIM * CDIM) / (256 * 4), 256, 0, stream>>>(w1, Wb);
        gemm1f_kernel<<<dim3(FFDIM / 128, TTOK / 128, NEXP), 256, 0, stream>>>(
            xb, Wb, b1, counts, offsets, btok, H);
        cast_kernel<<<(NEXP * CDIM * FFDIM) / (256 * 4), 256, 0, stream>>>(w2, Wb);
        gemm2f_kernel<<<dim3(CDIM / 128, (TTOK / 128) * 2, NEXP), 256, 0, stream>>>(
            H, Wb, b2, counts, offsets, btok, bgate, out);
    } else {
        unsigned short* xb = (unsigned short*)(ws + ((size_t)1 << 20));
        unsigned short* H  = (unsigned short*)(ws + ((size_t)16 << 20));

        cast_kernel<<<(TTOK * CDIM) / (256 * 4), 256, 0, stream>>>(x, xb);
        router_kernel<<<TTOK / 4, 256, 0, stream>>>(x, rw, counts, btok, bgate);
        offsets_kernel<<<1, 64, 0, stream>>>(counts, offsets);
        gemm1_kernel<<<dim3(FFDIM / 128, TTOK / 128, NEXP), 256, 0, stream>>>(
            xb, w1, b1, counts, offsets, btok, H);
        gemm2_kernel<<<dim3(CDIM / 128, TTOK / 128, NEXP), 256, 0, stream>>>(
            H, w2, b2, counts, offsets, btok, bgate, out);
    }
}

// Round 3
// 691.441 us; speedup vs baseline: 1.0907x; 1.0245x over previous
//
#include <hip/hip_runtime.h>
#include <hip/hip_bf16.h>
#include <cstdint>

// Problem constants (B=2, N=2048 -> T=4096 tokens)
#define TTOK  4096
#define CDIM  1024
#define FFDIM 4096
#define NEXP  8

// Fast-path workspace layout (needs >= 137 MiB):
//   [0,64)            counts[8]   (memset 0 each launch)
//   [64, ..)          offsets[9]
//   [4K, 4K+128K)     btok[8][4096]
//   [132K, 132K+128K) bgate[8][4096]
//   [1MB, 9MB)        xb : x as bf16 [4096,1024]
//   [9MB, 73MB)       Wb : bf16 weights, shared between passes (W1 then W2), 64 MiB
//   [73MB, 137MB)     H  : gelu(X W1^T + b1) bf16, compacted [8192, 4096], 64 MiB

typedef short short8 __attribute__((ext_vector_type(8)));   // 8 bf16 in 4 VGPRs
typedef float f32x4 __attribute__((ext_vector_type(4)));

__device__ __forceinline__ unsigned short f2bf(float f) {
    unsigned int u = __float_as_uint(f);
    u = u + 0x7fffu + ((u >> 16) & 1u);   // round-to-nearest-even
    return (unsigned short)(u >> 16);
}

// async global -> LDS, 16 bytes per lane. LDS dest MUST be wave-uniform base + lane*16.
__device__ __forceinline__ void gl_lds16(const unsigned short* g, unsigned short* l) {
    __builtin_amdgcn_global_load_lds(
        (const __attribute__((address_space(1))) unsigned int*)g,
        (__attribute__((address_space(3))) unsigned int*)l, 16, 0, 0);
}

// ---------------- fp32 -> bf16 cast (x and weights) ----------------
__global__ void cast_kernel(const float* __restrict__ src, unsigned short* __restrict__ dst) {
    int i = blockIdx.x * blockDim.x + threadIdx.x;   // n/4 threads, exact division
    float4 v = reinterpret_cast<const float4*>(src)[i];
    ushort4 o;
    o.x = f2bf(v.x); o.y = f2bf(v.y); o.z = f2bf(v.z); o.w = f2bf(v.w);
    reinterpret_cast<ushort4*>(dst)[i] = o;
}

// ---------------- router: logits -> softmax -> top2 -> bucket scatter ----------------
__global__ void router_kernel(const float* __restrict__ x, const float* __restrict__ rw,
                              int* __restrict__ counts, int* __restrict__ btok,
                              float* __restrict__ bgate) {
    const int wave = threadIdx.x >> 6;
    const int lane = threadIdx.x & 63;
    const int t = blockIdx.x * 4 + wave;
    const float* xr = x + (size_t)t * CDIM;

    float acc[NEXP];
#pragma unroll
    for (int e = 0; e < NEXP; e++) acc[e] = 0.f;
    for (int c = lane; c < CDIM; c += 64) {
        float xv = xr[c];
#pragma unroll
        for (int e = 0; e < NEXP; e++) acc[e] += xv * rw[e * CDIM + c];
    }
#pragma unroll
    for (int e = 0; e < NEXP; e++) {
#pragma unroll
        for (int off = 32; off > 0; off >>= 1) acc[e] += __shfl_down(acc[e], off, 64);
    }
    if (lane == 0) {
        float mx = acc[0];
#pragma unroll
        for (int e = 1; e < NEXP; e++) mx = fmaxf(mx, acc[e]);
        float p[NEXP]; float s = 0.f;
#pragma unroll
        for (int e = 0; e < NEXP; e++) { p[e] = expf(acc[e] - mx); s += p[e]; }
        int i0 = 0;
#pragma unroll
        for (int e = 1; e < NEXP; e++) if (p[e] > p[i0]) i0 = e;
        int i1 = (i0 == 0) ? 1 : 0;
#pragma unroll
        for (int e = 0; e < NEXP; e++) if (e != i0 && p[e] > p[i1]) i1 = e;
        float pr0 = p[i0] / s, pr1 = p[i1] / s;
        float rs = 1.f / (pr0 + pr1 + 1e-9f);
        float w0 = pr0 * rs, w1 = pr1 * rs;
        int pos = atomicAdd(&counts[i0], 1);
        btok[i0 * TTOK + pos] = t; bgate[i0 * TTOK + pos] = w0;
        pos = atomicAdd(&counts[i1], 1);
        btok[i1 * TTOK + pos] = t; bgate[i1 * TTOK + pos] = w1;
    }
}

__global__ void offsets_kernel(const int* __restrict__ counts, int* __restrict__ offsets) {
    if (threadIdx.x == 0 && blockIdx.x == 0) {
        int s = 0;
        for (int e = 0; e < NEXP; e++) { offsets[e] = s; s += counts[e]; }
        offsets[NEXP] = s;
    }
}

// ===== FAST PATH: double-buffered async global_load_lds, 1 barrier per K-iter =====
// LDS layout per buffer (16 KB): As 128x32 bf16 (8 KB) | Bs 128x32 bf16 (8 KB).
// Two buffers = 32 KB. gemm1f reuses the first 16 KB as the output repack buffer.

// pass A: H = gelu(X W1b^T + b1), 128x128 tile, BK=32
__global__ __launch_bounds__(256) void gemm1f_kernel(
    const unsigned short* __restrict__ xb, const unsigned short* __restrict__ w1b,
    const float* __restrict__ b1, const int* __restrict__ counts,
    const int* __restrict__ offsets, const int* __restrict__ btok,
    unsigned short* __restrict__ H) {
    const int e = blockIdx.z;
    const int cnt = counts[e];
    const int m0 = blockIdx.y * 128;
    if (m0 >= cnt) return;
    const int n0 = blockIdx.x * 128;   // FF columns
    const int po = offsets[e];

    __shared__ uint4 smem4[2048];      // 32 KB
    unsigned short* smem = (unsigned short*)smem4;

    const int tid = threadIdx.x;
    const int wave = tid >> 6, lane = tid & 63;
    const int wm = (wave >> 1) << 6, wn = (wave & 1) << 6;
    const int lm = lane & 15, kq = lane >> 4;

    // staging: thread covers 16 B = 8 bf16; row = tid/4 (+64), col8 = (tid%4)*8
    const int sr = tid >> 2;
    const int sc = (tid & 3) << 3;
    const int tA0 = btok[e * TTOK + min(m0 + sr, cnt - 1)];
    const int tA1 = btok[e * TTOK + min(m0 + 64 + sr, cnt - 1)];
    const unsigned short* ga0 = xb + (size_t)tA0 * CDIM + sc;
    const unsigned short* ga1 = xb + (size_t)tA1 * CDIM + sc;
    const unsigned short* gb0 = w1b + ((size_t)e * FFDIM + n0 + sr) * CDIM + sc;
    const unsigned short* gb1 = gb0 + (size_t)64 * CDIM;

    f32x4 acc[4][4];
#pragma unroll
    for (int i = 0; i < 4; i++)
#pragma unroll
        for (int j = 0; j < 4; j++) { f32x4 z = {0.f, 0.f, 0.f, 0.f}; acc[i][j] = z; }

    // prologue: issue buf0 loads
    {
        unsigned short* base = smem;            // buf 0
        gl_lds16(ga0, base + tid * 8);
        gl_lds16(ga1, base + 64 * 32 + tid * 8);
        gl_lds16(gb0, base + 4096 + tid * 8);
        gl_lds16(gb1, base + 4096 + 64 * 32 + tid * 8);
    }

    for (int k0 = 0; k0 < CDIM; k0 += 32) {
        const int cur = (k0 >> 5) & 1;
        __syncthreads();                        // waits cur's loads (issued last iter)
        if (k0 + 32 < CDIM) {                   // prefetch next tile into other buffer
            unsigned short* base = smem + (cur ^ 1) * 8192;
            gl_lds16(ga0 + k0 + 32, base + tid * 8);
            gl_lds16(ga1 + k0 + 32, base + 64 * 32 + tid * 8);
            gl_lds16(gb0 + k0 + 32, base + 4096 + tid * 8);
            gl_lds16(gb1 + k0 + 32, base + 4096 + 64 * 32 + tid * 8);
        }
        const unsigned short* As = smem + cur * 8192;
        const unsigned short* Bs = As + 4096;
        short8 af[4], bfr[4];
#pragma unroll
        for (int i = 0; i < 4; i++) af[i] = *reinterpret_cast<const short8*>(&As[(wm + i * 16 + lm) * 32 + kq * 8]);
#pragma unroll
        for (int j = 0; j < 4; j++) bfr[j] = *reinterpret_cast<const short8*>(&Bs[(wn + j * 16 + lm) * 32 + kq * 8]);
#pragma unroll
        for (int i = 0; i < 4; i++)
#pragma unroll
            for (int j = 0; j < 4; j++)
                acc[i][j] = __builtin_amdgcn_mfma_f32_16x16x32_bf16(af[i], bfr[j], acc[i][j], 0, 0, 0);
    }
    __syncthreads();   // K-loop buffers dead; reuse first 16 KB as repack buffer

    float bias[4];
#pragma unroll
    for (int j = 0; j < 4; j++) bias[j] = b1[e * FFDIM + n0 + wn + j * 16 + lm];

    unsigned short* Cs = smem;   // 64 x 128 bf16 = 16 KB
#pragma unroll
    for (int p = 0; p < 2; p++) {
        if ((wave >> 1) == p) {
#pragma unroll
            for (int i = 0; i < 4; i++) {
#pragma unroll
                for (int r = 0; r < 4; r++) {
                    const int row = i * 16 + kq * 4 + r;   // 0..63 relative to p*64
#pragma unroll
                    for (int j = 0; j < 4; j++) {
                        float h = acc[i][j][r] + bias[j];
                        float g = 0.5f * h * (1.f + erff(h * 0.70710678118654752f));
                        Cs[row * 128 + wn + j * 16 + lm] = f2bf(g);
                    }
                }
            }
        }
        __syncthreads();
#pragma unroll
        for (int q = 0; q < 4; q++) {
            const int c = q * 256 + tid;
            const int row = c >> 4;
            const int col8 = (c & 15) << 3;
            const int mrow = m0 + p * 64 + row;
            if (mrow < cnt)
                *reinterpret_cast<uint4*>(&H[(size_t)(po + mrow) * FFDIM + n0 + col8]) =
                    *reinterpret_cast<const uint4*>(&Cs[row * 128 + col8]);
        }
        __syncthreads();
    }
}

// pass B: out += gate * (H W2b^T + b2), split-K=2, atomic scatter epilogue
__global__ __launch_bounds__(256) void gemm2f_kernel(
    const unsigned short* __restrict__ H, const unsigned short* __restrict__ w2b,
    const float* __restrict__ b2, const int* __restrict__ counts,
    const int* __restrict__ offsets, const int* __restrict__ btok,
    const float* __restrict__ bgate, float* __restrict__ out) {
    const int e = blockIdx.z;
    const int cnt = counts[e];
    const int m0 = (blockIdx.y >> 1) * 128;
    const int ks = blockIdx.y & 1;             // K split: [ks*2048, ks*2048+2048)
    if (m0 >= cnt) return;
    const int n0 = blockIdx.x * 128;           // C columns
    const int po = offsets[e];

    __shared__ uint4 smem4[2048];              // 32 KB
    unsigned short* smem = (unsigned short*)smem4;

    const int tid = threadIdx.x;
    const int wave = tid >> 6, lane = tid & 63;
    const int wm = (wave >> 1) << 6, wn = (wave & 1) << 6;
    const int lm = lane & 15, kq = lane >> 4;

    const int sr = tid >> 2;
    const int sc = (tid & 3) << 3;
    const int r0 = min(m0 + sr, cnt - 1);
    const int r1 = min(m0 + 64 + sr, cnt - 1);
    const unsigned short* ga0 = H + (size_t)(po + r0) * FFDIM + ks * 2048 + sc;
    const unsigned short* ga1 = H + (size_t)(po + r1) * FFDIM + ks * 2048 + sc;
    const unsigned short* gb0 = w2b + ((size_t)e * CDIM + n0 + sr) * FFDIM + ks * 2048 + sc;
    const unsigned short* gb1 = gb0 + (size_t)64 * FFDIM;

    f32x4 acc[4][4];
#pragma unroll
    for (int i = 0; i < 4; i++)
#pragma unroll
        for (int j = 0; j < 4; j++) { f32x4 z = {0.f, 0.f, 0.f, 0.f}; acc[i][j] = z; }

    {
        unsigned short* base = smem;            // buf 0
        gl_lds16(ga0, base + tid * 8);
        gl_lds16(ga1, base + 64 * 32 + tid * 8);
        gl_lds16(gb0, base + 4096 + tid * 8);
        gl_lds16(gb1, base + 4096 + 64 * 32 + tid * 8);
    }

    for (int k0 = 0; k0 < 2048; k0 += 32) {
        const int cur = (k0 >> 5) & 1;
        __syncthreads();
        if (k0 + 32 < 2048) {
            unsigned short* base = smem + (cur ^ 1) * 8192;
            gl_lds16(ga0 + k0 + 32, base + tid * 8);
            gl_lds16(ga1 + k0 + 32, base + 64 * 32 + tid * 8);
            gl_lds16(gb0 + k0 + 32, base + 4096 + tid * 8);
            gl_lds16(gb1 + k0 + 32, base + 4096 + 64 * 32 + tid * 8);
        }
        const unsigned short* As = smem + cur * 8192;
        const unsigned short* Bs = As + 4096;
        short8 af[4], bfr[4];
#pragma unroll
        for (int i = 0; i < 4; i++) af[i] = *reinterpret_cast<const short8*>(&As[(wm + i * 16 + lm) * 32 + kq * 8]);
#pragma unroll
        for (int j = 0; j < 4; j++) bfr[j] = *reinterpret_cast<const short8*>(&Bs[(wn + j * 16 + lm) * 32 + kq * 8]);
#pragma unroll
        for (int i = 0; i < 4; i++)
#pragma unroll
            for (int j = 0; j < 4; j++)
                acc[i][j] = __builtin_amdgcn_mfma_f32_16x16x32_bf16(af[i], bfr[j], acc[i][j], 0, 0, 0);
    }

    float bias[4];
#pragma unroll
    for (int j = 0; j < 4; j++) bias[j] = (ks == 0) ? b2[e * CDIM + n0 + wn + j * 16 + lm] : 0.f;

#pragma unroll
    for (int i = 0; i < 4; i++) {
#pragma unroll
        for (int r = 0; r < 4; r++) {
            const int mrow = m0 + wm + i * 16 + kq * 4 + r;
            if (mrow < cnt) {
                const int tok = btok[e * TTOK + mrow];
                const float g = bgate[e * TTOK + mrow];
                float* orow = out + (size_t)tok * CDIM;
#pragma unroll
                for (int j = 0; j < 4; j++)
                    atomicAdd(orow + n0 + wn + j * 16 + lm, g * (acc[i][j][r] + bias[j]));
            }
        }
    }
}

// ================= SLOW FALLBACK (round-1 kernels, in-loop fp32->bf16) =================

__global__ __launch_bounds__(256) void gemm1_kernel(
    const unsigned short* __restrict__ xb, const float* __restrict__ w1,
    const float* __restrict__ b1, const int* __restrict__ counts,
    const int* __restrict__ offsets, const int* __restrict__ btok,
    unsigned short* __restrict__ H) {
    const int e = blockIdx.z;
    const int cnt = counts[e];
    const int m0 = blockIdx.y * 128;
    if (m0 >= cnt) return;
    const int n0 = blockIdx.x * 128;
    const int po = offsets[e];

    __shared__ unsigned short As[128][32];
    __shared__ unsigned short Bs[128][32];

    const int tid = threadIdx.x;
    const int wave = tid >> 6, lane = tid & 63;
    const int wm = (wave >> 1) << 6, wn = (wave & 1) << 6;
    const int lm = lane & 15, kq = lane >> 4;

    f32x4 acc[4][4];
#pragma unroll
    for (int i = 0; i < 4; i++)
#pragma unroll
        for (int j = 0; j < 4; j++) { f32x4 z = {0.f, 0.f, 0.f, 0.f}; acc[i][j] = z; }

    const float* w1e = w1 + (size_t)e * FFDIM * CDIM;
    const int arow = tid >> 1;
    const int acolb = (tid & 1) * 16;
    int tokA = -1;
    if (m0 + arow < cnt) tokA = btok[e * TTOK + m0 + arow];
    const int brow = tid >> 1;
    const int bcol = (tid & 1) * 16;

    for (int k0 = 0; k0 < CDIM; k0 += 32) {
        uint4 a0 = {0, 0, 0, 0}, a1 = {0, 0, 0, 0};
        if (tokA >= 0) {
            const uint4* src = reinterpret_cast<const uint4*>(xb + (size_t)tokA * CDIM + k0 + acolb);
            a0 = src[0]; a1 = src[1];
        }
        *reinterpret_cast<uint4*>(&As[arow][acolb]) = a0;
        *reinterpret_cast<uint4*>(&As[arow][acolb + 8]) = a1;
        {
            const float* src = w1e + (size_t)(n0 + brow) * CDIM + k0 + bcol;
            ushort4* dst = reinterpret_cast<ushort4*>(&Bs[brow][bcol]);
#pragma unroll
            for (int q = 0; q < 4; q++) {
                float4 v = reinterpret_cast<const float4*>(src)[q];
                ushort4 o; o.x = f2bf(v.x); o.y = f2bf(v.y); o.z = f2bf(v.z); o.w = f2bf(v.w);
                dst[q] = o;
            }
        }
        __syncthreads();
        short8 af[4], bfr[4];
#pragma unroll
        for (int i = 0; i < 4; i++) af[i] = *reinterpret_cast<const short8*>(&As[wm + i * 16 + lm][kq * 8]);
#pragma unroll
        for (int j = 0; j < 4; j++) bfr[j] = *reinterpret_cast<const short8*>(&Bs[wn + j * 16 + lm][kq * 8]);
#pragma unroll
        for (int i = 0; i < 4; i++)
#pragma unroll
            for (int j = 0; j < 4; j++)
                acc[i][j] = __builtin_amdgcn_mfma_f32_16x16x32_bf16(af[i], bfr[j], acc[i][j], 0, 0, 0);
        __syncthreads();
    }

#pragma unroll
    for (int j = 0; j < 4; j++) {
        const int fcol = n0 + wn + j * 16 + lm;
        const float bias = b1[e * FFDIM + fcol];
#pragma unroll
        for (int i = 0; i < 4; i++) {
#pragma unroll
            for (int r = 0; r < 4; r++) {
                const int mrow = m0 + wm + i * 16 + kq * 4 + r;
                if (mrow < cnt) {
                    float h = acc[i][j][r] + bias;
                    float g = 0.5f * h * (1.f + erff(h * 0.70710678118654752f));
                    H[(size_t)(po + mrow) * FFDIM + fcol] = f2bf(g);
                }
            }
        }
    }
}

__global__ __launch_bounds__(256) void gemm2_kernel(
    const unsigned short* __restrict__ H, const float* __restrict__ w2,
    const float* __restrict__ b2, const int* __restrict__ counts,
    const int* __restrict__ offsets, const int* __restrict__ btok,
    const float* __restrict__ bgate, float* __restrict__ out) {
    const int e = blockIdx.z;
    const int cnt = counts[e];
    const int m0 = blockIdx.y * 128;
    if (m0 >= cnt) return;
    const int n0 = blockIdx.x * 128;
    const int po = offsets[e];

    __shared__ unsigned short As[128][32];
    __shared__ unsigned short Bs[128][32];

    const int tid = threadIdx.x;
    const int wave = tid >> 6, lane = tid & 63;
    const int wm = (wave >> 1) << 6, wn = (wave & 1) << 6;
    const int lm = lane & 15, kq = lane >> 4;

    f32x4 acc[4][4];
#pragma unroll
    for (int i = 0; i < 4; i++)
#pragma unroll
        for (int j = 0; j < 4; j++) { f32x4 z = {0.f, 0.f, 0.f, 0.f}; acc[i][j] = z; }

    const float* w2e = w2 + (size_t)e * CDIM * FFDIM;
    const int arow = tid >> 1;
    const int acolb = (tid & 1) * 16;
    const bool aval = (m0 + arow < cnt);
    const unsigned short* asrc = H + (size_t)(po + m0 + arow) * FFDIM + acolb;
    const int brow = tid >> 1;
    const int bcol = (tid & 1) * 16;

    for (int k0 = 0; k0 < FFDIM; k0 += 32) {
        uint4 a0 = {0, 0, 0, 0}, a1 = {0, 0, 0, 0};
        if (aval) {
            const uint4* src = reinterpret_cast<const uint4*>(asrc + k0);
            a0 = src[0]; a1 = src[1];
        }
        *reinterpret_cast<uint4*>(&As[arow][acolb]) = a0;
        *reinterpret_cast<uint4*>(&As[arow][acolb + 8]) = a1;
        {
            const float* src = w2e + (size_t)(n0 + brow) * FFDIM + k0 + bcol;
            ushort4* dst = reinterpret_cast<ushort4*>(&Bs[brow][bcol]);
#pragma unroll
            for (int q = 0; q < 4; q++) {
                float4 v = reinterpret_cast<const float4*>(src)[q];
                ushort4 o; o.x = f2bf(v.x); o.y = f2bf(v.y); o.z = f2bf(v.z); o.w = f2bf(v.w);
                dst[q] = o;
            }
        }
        __syncthreads();
        short8 af[4], bfr[4];
#pragma unroll
        for (int i = 0; i < 4; i++) af[i] = *reinterpret_cast<const short8*>(&As[wm + i * 16 + lm][kq * 8]);
#pragma unroll
        for (int j = 0; j < 4; j++) bfr[j] = *reinterpret_cast<const short8*>(&Bs[wn + j * 16 + lm][kq * 8]);
#pragma unroll
        for (int i = 0; i < 4; i++)
#pragma unroll
            for (int j = 0; j < 4; j++)
                acc[i][j] = __builtin_amdgcn_mfma_f32_16x16x32_bf16(af[i], bfr[j], acc[i][j], 0, 0, 0);
        __syncthreads();
    }

    float bias[4];
#pragma unroll
    for (int j = 0; j < 4; j++) bias[j] = b2[e * CDIM + n0 + wn + j * 16 + lm];

#pragma unroll
    for (int i = 0; i < 4; i++) {
#pragma unroll
        for (int r = 0; r < 4; r++) {
            const int mrow = m0 + wm + i * 16 + kq * 4 + r;
            if (mrow < cnt) {
                const int tok = btok[e * TTOK + mrow];
                const float g = bgate[e * TTOK + mrow];
                float* orow = out + (size_t)tok * CDIM;
#pragma unroll
                for (int j = 0; j < 4; j++) {
                    const int c = n0 + wn + j * 16 + lm;
                    atomicAdd(orow + c, g * (acc[i][j][r] + bias[j]));
                }
            }
        }
    }
}

extern "C" void kernel_launch(void* const* d_in, const int* in_sizes, int n_in,
                              void* d_out, int out_size, void* d_ws, size_t ws_size,
                              hipStream_t stream) {
    const float* x  = (const float*)d_in[0];
    const float* rw = (const float*)d_in[1];
    const float* w1 = (const float*)d_in[2];
    const float* b1 = (const float*)d_in[3];
    const float* w2 = (const float*)d_in[4];
    const float* b2 = (const float*)d_in[5];
    float* out = (float*)d_out;

    char* ws = (char*)d_ws;
    int*   counts  = (int*)ws;
    int*   offsets = (int*)(ws + 64);
    int*   btok    = (int*)(ws + 4096);
    float* bgate   = (float*)(ws + 4096 + 131072);

    hipMemsetAsync(d_out, 0, (size_t)out_size * sizeof(float), stream);
    hipMemsetAsync(counts, 0, 64, stream);

    const bool fast = ws_size >= ((size_t)137 << 20);

    if (fast) {
        unsigned short* xb = (unsigned short*)(ws + ((size_t)1 << 20));
        unsigned short* Wb = (unsigned short*)(ws + ((size_t)9 << 20));    // 64 MiB shared W1b/W2b
        unsigned short* H  = (unsigned short*)(ws + ((size_t)73 << 20));   // 64 MiB

        cast_kernel<<<(TTOK * CDIM) / (256 * 4), 256, 0, stream>>>(x, xb);
        router_kernel<<<TTOK / 4, 256, 0, stream>>>(x, rw, counts, btok, bgate);
        offsets_kernel<<<1, 64, 0, stream>>>(counts, offsets);
        cast_kernel<<<(NEXP * FFDIM * CDIM) / (256 * 4), 256, 0, stream>>>(w1, Wb);
        gemm1f_kernel<<<dim3(FFDIM / 128, TTOK / 128, NEXP), 256, 0, stream>>>(
            xb, Wb, b1, counts, offsets, btok, H);
        cast_kernel<<<(NEXP * CDIM * FFDIM) / (256 * 4), 256, 0, stream>>>(w2, Wb);
        gemm2f_kernel<<<dim3(CDIM / 128, (TTOK / 128) * 2, NEXP), 256, 0, stream>>>(
            H, Wb, b2, counts, offsets, btok, bgate, out);
    } else {
        unsigned short* xb = (unsigned short*)(ws + ((size_t)1 << 20));
        unsigned short* H  = (unsigned short*)(ws + ((size_t)16 << 20));

        cast_kernel<<<(TTOK * CDIM) / (256 * 4), 256, 0, stream>>>(x, xb);
        router_kernel<<<TTOK / 4, 256, 0, stream>>>(x, rw, counts, btok, bgate);
        offsets_kernel<<<1, 64, 0, stream>>>(counts, offsets);
        gemm1_kernel<<<dim3(FFDIM / 128, TTOK / 128, NEXP), 256, 0, stream>>>(
            xb, w1, b1, counts, offsets, btok, H);
        gemm2_kernel<<<dim3(CDIM / 128, TTOK / 128, NEXP), 256, 0, stream>>>(
            H, w2, b2, counts, offsets, btok, bgate, out);
    }
}